// Round 9
// baseline (333.849 us; speedup 1.0000x reference)
//
#include <hip/hip_runtime.h>
#include <hip/hip_bf16.h>
#include <stdint.h>

#define DI __device__ __forceinline__

typedef __bf16 bf16x4 __attribute__((ext_vector_type(4)));
typedef __bf16 bf16x8 __attribute__((ext_vector_type(8)));
typedef float  f32x4  __attribute__((ext_vector_type(4)));

static constexpr int  BATCH = 4;
static constexpr int  SEQ   = 4096;
static constexpr int  DIM   = 768;
static constexpr long TOK   = (long)BATCH * SEQ;        // 16384
static constexpr int  QT    = SEQ / 128;                // 32 q-tiles per batch
static constexpr int  NTRI  = QT * (QT + 1) / 2;        // 528 causal 128x128 tiles
static constexpr float SCALE = 0.0360843918243516150f;  // 1/sqrt(768)

// ---------------- fp32 -> bf16 convert (weights only) ----------------
__global__ void cvt4_kernel(const float* __restrict__ a, const float* __restrict__ b,
                            const float* __restrict__ c, const float* __restrict__ d,
                            __bf16* __restrict__ oa, __bf16* __restrict__ ob,
                            __bf16* __restrict__ oc, __bf16* __restrict__ od, long n4){
  const float* in  = blockIdx.y == 0 ? a : blockIdx.y == 1 ? b : blockIdx.y == 2 ? c : d;
  __bf16*      out = blockIdx.y == 0 ? oa : blockIdx.y == 1 ? ob : blockIdx.y == 2 ? oc : od;
  long i = (long)blockIdx.x * blockDim.x + threadIdx.x;
  const long stride = (long)gridDim.x * blockDim.x;
  for(; i < n4; i += stride){
    float4 v = ((const float4*)in)[i];
    bf16x4 o = { (__bf16)v.x, (__bf16)v.y, (__bf16)v.z, (__bf16)v.w };
    ((bf16x4*)out)[i] = o;
  }
}

// ================= proven 2-phase core =================
// LDS tile: [R rows][64 bf16 = 8 chunks of 16B], chunk XOR-swizzled by (row&7).
DI int swz_off(int r, int c){ return (r << 7) + ((c ^ (r & 7)) << 4); }

// bf16 source: global_load_lds, pre-swizzled global source chunk, linear LDS dest.
template<int R>
DI void stage(const __bf16* __restrict__ src, long ld, char* lds, int tid){
  const int w = tid >> 6, l = tid & 63;
  const int rsub = l >> 3;
  const int kc   = (l & 7) ^ rsub;
  const __bf16* g = src + (long)(w * 8 + rsub) * ld + kc * 8;
  char* d = lds + (w << 10);
  #pragma unroll
  for(int i = 0; i < R / 64; ++i){
    __builtin_amdgcn_global_load_lds(
        (const __attribute__((address_space(1))) void*)(g + (long)(i * 64) * ld),
        (__attribute__((address_space(3))) void*)(d + i * 8192), 16, 0, 0);
  }
}

// dual bf16 source, summed (oproj A = att0 + att1), same layout.
template<int R>
DI void stage_add(const __bf16* __restrict__ a0, const __bf16* __restrict__ a1,
                  long ld, char* lds, int tid){
  const int w = tid >> 6, l = tid & 63;
  const int rsub = l >> 3;
  const int kc   = (l & 7) ^ rsub;
  const long off = (long)(w * 8 + rsub) * ld + kc * 8;
  char* d = lds + (w << 10) + (l << 4);
  #pragma unroll
  for(int i = 0; i < R / 64; ++i){
    bf16x8 v0 = *(const bf16x8*)(a0 + off + (long)(i * 64) * ld);
    bf16x8 v1 = *(const bf16x8*)(a1 + off + (long)(i * 64) * ld);
    bf16x8 o;
    #pragma unroll
    for(int e = 0; e < 8; ++e) o[e] = (__bf16)((float)v0[e] + (float)v1[e]);
    *(bf16x8*)(d + i * 8192) = o;
  }
}

DI bf16x8 frag_ld(const char* lds, int row, int c){
  return *(const bf16x8*)(lds + swz_off(row, c));
}

// One K=64 step: 32 MFMAs per wave (4x4 frags x 2 k-halves).
DI void mma_tile(const char* As, const char* Bs, int lane, int wr, int wc, f32x4 acc[4][4]){
  #pragma unroll
  for(int kk = 0; kk < 2; ++kk){
    const int c = kk * 4 + (lane >> 4);
    bf16x8 a[4], b[4];
    #pragma unroll
    for(int i = 0; i < 4; ++i) a[i] = frag_ld(As, wr + i * 16 + (lane & 15), c);
    #pragma unroll
    for(int j = 0; j < 4; ++j) b[j] = frag_ld(Bs, wc + j * 16 + (lane & 15), c);
    #pragma unroll
    for(int i = 0; i < 4; ++i)
      #pragma unroll
      for(int j = 0; j < 4; ++j)
        acc[i][j] = __builtin_amdgcn_mfma_f32_16x16x32_bf16(a[i], b[j], acc[i][j], 0, 0, 0);
  }
}

// Single-buffered 128x256 K-loop (48KB LDS -> 3 blocks/CU), all-bf16 operands.
template<class FA, class FB>
DI void kloop2(FA fa, long lda, FB fb, long ldb, int nt, int tid,
               char* As, char* Bs, f32x4 acc[4][4]){
  const int lane = tid & 63, w = tid >> 6;
  const int wr = (w >> 2) * 64, wc = (w & 3) * 64;
  for(int t = 0; t < nt; ++t){
    stage<128>(fa(t), lda, As, tid);
    stage<256>(fb(t), ldb, Bs, tid);
    __syncthreads();
    mma_tile(As, Bs, lane, wr, wc, acc);
    __syncthreads();
  }
}

// ---- T14 K-loop for mixed f32/bf16 operands (proj): 128 rows f32 reg-staged
// with next-tile prefetch kept in flight across a counted vmcnt(4) + raw
// barrier; 256 rows bf16 via global_load_lds. Issue order fixed by "memory"
// fences so the FIFO vmcnt(4) completes exactly the 4 bf16 gloads.
template<int NT>
DI void kloop_t14(const float* gf32, long ldf, char* dfw,
                  const __bf16* gbf, long ldb, char* dbf,
                  const char* LA, const char* LB,
                  int lane, int wr, int wc, f32x4 acc[4][4]){
  float4 p0, p1, p2, p3;
  auto ldr = [&](int t){
    const float* g0 = gf32 + t * 64;
    const float* g1 = g0 + (long)64 * ldf;
    p0 = ((const float4*)g0)[0]; p1 = ((const float4*)g0)[1];
    p2 = ((const float4*)g1)[0]; p3 = ((const float4*)g1)[1];
  };
  ldr(0);
  for(int t = 0; t < NT; ++t){
    bf16x8 o0 = { (__bf16)p0.x, (__bf16)p0.y, (__bf16)p0.z, (__bf16)p0.w,
                  (__bf16)p1.x, (__bf16)p1.y, (__bf16)p1.z, (__bf16)p1.w };
    bf16x8 o1 = { (__bf16)p2.x, (__bf16)p2.y, (__bf16)p2.z, (__bf16)p2.w,
                  (__bf16)p3.x, (__bf16)p3.y, (__bf16)p3.z, (__bf16)p3.w };
    *(bf16x8*)dfw = o0;
    *(bf16x8*)(dfw + 8192) = o1;
    #pragma unroll
    for(int i = 0; i < 4; ++i)
      __builtin_amdgcn_global_load_lds(
          (const __attribute__((address_space(1))) void*)(gbf + t * 64 + (long)(i * 64) * ldb),
          (__attribute__((address_space(3))) void*)(dbf + i * 8192), 16, 0, 0);
    asm volatile("" ::: "memory");                   // pin: gloads before prefetch
    if(t + 1 < NT){
      ldr(t + 1);                                    // 4 f32 loads stay in flight
      asm volatile("s_waitcnt vmcnt(4) lgkmcnt(0)" ::: "memory");
    } else {
      asm volatile("s_waitcnt vmcnt(0) lgkmcnt(0)" ::: "memory");
    }
    __builtin_amdgcn_s_barrier();
    mma_tile(LA, LB, lane, wr, wc, acc);
    asm volatile("" ::: "memory");
    __builtin_amdgcn_s_barrier();
  }
}

// ---------------- fused Q/K/V^T projections (one dispatch, 3x384 blocks) --------
// z<2 : C = x @ W^T   — A = x (f32, 128 rows, T14 reg-staged), B = W (bf16, 256)
// z==2: vbT = Wv @ v^T — A = Wv (bf16, 256 rows, gload),  B = value (f32, 128, T14)
__global__ __launch_bounds__(512)
void proj_qkv(const float* __restrict__ query, const float* __restrict__ key_,
              const float* __restrict__ value, const __bf16* __restrict__ Wqb,
              const __bf16* __restrict__ Wkb, const __bf16* __restrict__ Wvb,
              const float* __restrict__ bq, const float* __restrict__ bk,
              const float* __restrict__ bv, __bf16* __restrict__ qb,
              __bf16* __restrict__ kb, __bf16* __restrict__ vbT){
  __shared__ __attribute__((aligned(128))) char L[49152];
  const int z = blockIdx.y, bid = blockIdx.x, tid = threadIdx.x;
  const int lane = tid & 63, w = tid >> 6, l = tid & 63;
  const int rsub = l >> 3, kc = (l & 7) ^ rsub;
  const int cl = lane & 15, rq = (lane >> 4) * 4;
  f32x4 acc[4][4] = {};

  if(z < 2){
    const float*  X = z ? key_ : query;
    const __bf16* W = z ? Wkb : Wqb;
    const float*  bias = z ? bk : bq;
    __bf16*       C = z ? kb : qb;
    const long m0 = (long)(bid / 3) * 128, n0 = (bid % 3) * 256;
    char* LA = L;                     // 16 KB (f32-cvt dest)
    char* LB = L + 16384;             // 32 KB (bf16 gload dest)
    const float*  gf = X + (m0 + w * 8 + rsub) * DIM + kc * 8;
    const __bf16* gb = W + (n0 + w * 8 + rsub) * DIM + kc * 8;
    const int wr = (w >> 2) * 64, wc = (w & 3) * 64;      // 2M x 4N
    kloop_t14<DIM / 64>(gf, DIM, LA + (w << 10) + (l << 4),
                        gb, DIM, LB + (w << 10), LA, LB, lane, wr, wc, acc);
    #pragma unroll
    for(int i = 0; i < 4; ++i)
      #pragma unroll
      for(int j = 0; j < 4; ++j){
        const long gc = n0 + wc + j * 16 + cl;
        #pragma unroll
        for(int e = 0; e < 4; ++e){
          const long gr = m0 + wr + i * 16 + rq + e;
          C[gr * DIM + gc] = (__bf16)(acc[i][j][e] + bias[gc]);
        }
      }
  } else {
    const long m0 = (long)(bid / 128) * 256, n0 = (long)(bid % 128) * 128;
    char* LA = L;                     // 32 KB (Wv bf16 gload dest)
    char* LB = L + 32768;             // 16 KB (value f32-cvt dest)
    const __bf16* ga = Wvb + (m0 + w * 8 + rsub) * DIM + kc * 8;
    const float*  gf = value + (n0 + w * 8 + rsub) * DIM + kc * 8;
    const int wr = (w >> 1) * 64, wc = (w & 1) * 64;      // 4M x 2N
    kloop_t14<DIM / 64>(gf, DIM, LB + (w << 10) + (l << 4),
                        ga, DIM, LA + (w << 10), LA, LB, lane, wr, wc, acc);
    #pragma unroll
    for(int i = 0; i < 4; ++i)
      #pragma unroll
      for(int j = 0; j < 4; ++j){
        const long gc = n0 + wc + j * 16 + cl;
        #pragma unroll
        for(int e = 0; e < 4; ++e){
          const long gr = m0 + wr + i * 16 + rq + e;
          vbT[gr * TOK + gc] = (__bf16)(acc[i][j][e] + bv[gr]);
        }
      }
  }
}

// ---------------- QK^T: 2-phase 256q x 128k, fused exp + atomic row-sums --------
__global__ __launch_bounds__(512)
void qk_kernel(const __bf16* __restrict__ qb, const __bf16* __restrict__ kb,
               __bf16* __restrict__ Pc, float* __restrict__ rlsum){
  const int b = blockIdx.y, t2 = blockIdx.x, tid = threadIdx.x;
  int Qi = (int)((sqrtf(4.0f * t2 + 1.0f) - 1.0f) * 0.5f);
  while((Qi + 1) * (Qi + 2) <= t2) Qi++;
  while(Qi * (Qi + 1) > t2) Qi--;
  const int ki = t2 - Qi * (Qi + 1);
  const __bf16* Aq = qb + ((long)b * SEQ + Qi * 256) * DIM;
  const __bf16* Bk = kb + ((long)b * SEQ + ki * 128) * DIM;
  __shared__ __attribute__((aligned(128))) char As[32768];
  __shared__ __attribute__((aligned(128))) char Bs[16384];
  const int lane = tid & 63, w = tid >> 6;
  const int wr = (w >> 1) * 64, wc = (w & 1) * 64;   // 4M x 2N waves
  f32x4 acc[4][4] = {};
  for(int t = 0; t < DIM / 64; ++t){
    stage<256>(Aq + t * 64, DIM, As, tid);
    stage<128>(Bk + t * 64, DIM, Bs, tid);
    __syncthreads();
    mma_tile(As, Bs, lane, wr, wc, acc);
    __syncthreads();
  }
  const int cl = lane & 15, rq = (lane >> 4) * 4;
  #pragma unroll
  for(int i = 0; i < 4; ++i){
    const int rbase = wr + i * 16;                    // 0..255
    const int qi = 2 * Qi + (rbase >> 7);
    if(ki > qi) continue;                             // fully-masked half-tile
    const bool diag = (ki == qi);
    __bf16* tile = Pc + ((long)b * NTRI + (long)qi * (qi + 1) / 2 + ki) * 16384;
    float rsum[4] = {0.f, 0.f, 0.f, 0.f};
    #pragma unroll
    for(int j = 0; j < 4; ++j){
      const int c = wc + j * 16 + cl;
      #pragma unroll
      for(int e = 0; e < 4; ++e){
        const int rloc = (rbase + rq + e) & 127;
        float p = (diag && c > rloc) ? 0.0f
                  : __expf(fminf(acc[i][j][e] * SCALE, 30.0f));
        tile[rloc * 128 + c] = (__bf16)p;
        rsum[e] += p;
      }
    }
    #pragma unroll
    for(int e = 0; e < 4; ++e){                       // reduce across 16 col-lanes
      float s = rsum[e];
      s += __shfl_xor(s, 1); s += __shfl_xor(s, 2);
      s += __shfl_xor(s, 4); s += __shfl_xor(s, 8);
      if(cl == 0){
        const long gr = (long)b * SEQ + Qi * 256 + rbase + rq + e;
        atomicAdd(&rlsum[gr], s);
      }
    }
  }
}

// ---------------- P.V: K-split 128x256 GEMM, partials to att0/att1 ----------
__global__ __launch_bounds__(512)
void pv_kernel(const __bf16* __restrict__ Pc, const float* __restrict__ rlsum,
               const __bf16* __restrict__ vbT, __bf16* __restrict__ att0,
               __bf16* __restrict__ att1){
  __shared__ __attribute__((aligned(128))) char As[16384];
  __shared__ __attribute__((aligned(128))) char Bs[32768];
  __shared__ float sRl[128];
  const int x = blockIdx.x, y = blockIdx.y, tid = threadIdx.x;
  const long n0 = (long)(x >> 2) * 256;
  const int b = x & 3;
  int qi, k0, k1, half;
  if(y == 62){ qi = 0; k0 = 0; k1 = 1; half = 0; }
  else{
    qi = 31 - (y >> 1); half = y & 1;
    const int c0 = (qi + 2) >> 1;
    if(half == 0){ k0 = 0; k1 = c0; } else { k0 = c0; k1 = qi + 1; }
  }
  if(tid < 128) sRl[tid] = 1.0f / rlsum[b * SEQ + qi * 128 + tid];
  const __bf16* Pq = Pc + ((long)b * NTRI + (long)qi * (qi + 1) / 2) * 16384;
  const __bf16* Bv = vbT + n0 * TOK + (long)b * SEQ;
  f32x4 acc[4][4] = {};
  auto fa = [&](int t){ return Pq + (long)(k0 + (t >> 1)) * 16384 + (t & 1) * 64; };
  auto fb = [&](int t){ return Bv + (long)k0 * 128 + t * 64; };
  kloop2(fa, 128, fb, TOK, 2 * (k1 - k0), tid, As, Bs, acc);  // barriers cover sRl

  __bf16* dst = half ? att1 : att0;
  const int lane = tid & 63, w = tid >> 6;
  const int wr = (w >> 2) * 64, wc = (w & 3) * 64;
  const int cl = lane & 15, rq = (lane >> 4) * 4;
  #pragma unroll
  for(int i = 0; i < 4; ++i)
    #pragma unroll
    for(int j = 0; j < 4; ++j){
      const long gc = n0 + wc + j * 16 + cl;
      #pragma unroll
      for(int e = 0; e < 4; ++e){
        const int rloc = wr + i * 16 + rq + e;
        float v = acc[i][j][e] * sRl[rloc];
        dst[((long)b * SEQ + qi * 128 + rloc) * DIM + gc] = (__bf16)v;
      }
    }
}

// ---------------- output projection: A = att0+att1 (fused add) -> fp32 ----------
__global__ __launch_bounds__(512)
void oproj(const __bf16* __restrict__ att0, const __bf16* __restrict__ att1,
           const __bf16* __restrict__ Wob, const float* __restrict__ bo,
           float* __restrict__ out){
  __shared__ __attribute__((aligned(128))) char As[16384];
  __shared__ __attribute__((aligned(128))) char Bs[32768];
  const int bid = blockIdx.x, tid = threadIdx.x;
  const long n0 = (bid % 3) * 256, m0 = (long)(bid / 3) * 128;
  const __bf16* Br = Wob + n0 * DIM;
  f32x4 acc[4][4] = {};
  const int lane = tid & 63, w = tid >> 6;
  const int wr = (w >> 2) * 64, wc = (w & 3) * 64;
  for(int t = 0; t < DIM / 64; ++t){
    stage_add<128>(att0 + m0 * DIM + t * 64, att1 + m0 * DIM + t * 64, DIM, As, tid);
    stage<256>(Br + t * 64, DIM, Bs, tid);
    __syncthreads();
    mma_tile(As, Bs, lane, wr, wc, acc);
    __syncthreads();
  }
  const int cl = lane & 15, rq = (lane >> 4) * 4;
  #pragma unroll
  for(int i = 0; i < 4; ++i)
    #pragma unroll
    for(int j = 0; j < 4; ++j){
      const long gc = n0 + wc + j * 16 + cl;
      #pragma unroll
      for(int e = 0; e < 4; ++e){
        const long gr = m0 + wr + i * 16 + rq + e;
        out[gr * DIM + gc] = acc[i][j][e] + bo[gc];
      }
    }
}

// ---------------- launch ----------------
extern "C" void kernel_launch(void* const* d_in, const int* in_sizes, int n_in,
                              void* d_out, int out_size, void* d_ws, size_t ws_size,
                              hipStream_t stream){
  const float* query = (const float*)d_in[0];
  const float* key_  = (const float*)d_in[1];
  const float* value = (const float*)d_in[2];
  const float* Wq = (const float*)d_in[3];
  const float* bq = (const float*)d_in[4];
  const float* Wk = (const float*)d_in[5];
  const float* bk = (const float*)d_in[6];
  const float* Wv = (const float*)d_in[7];
  const float* bv = (const float*)d_in[8];
  const float* Wo = (const float*)d_in[9];
  const float* bo = (const float*)d_in[10];
  // d_in[11]: causal tril mask — implemented structurally (block-triangular P).

  char* p = (char*)d_ws;
  auto carve = [&](size_t bytes)->char*{
    char* r = p; p += (bytes + 255) & ~(size_t)255; return r;
  };
  const size_t tb = (size_t)TOK * DIM * 2;   // 25.2 MB
  __bf16* qb   = (__bf16*)carve(tb);
  __bf16* kb   = (__bf16*)carve(tb);
  __bf16* vbT  = (__bf16*)carve(tb);
  __bf16* att0 = (__bf16*)carve(tb);
  __bf16* att1 = (__bf16*)carve(tb);
  __bf16* Wqb = (__bf16*)carve((size_t)DIM * DIM * 2);
  __bf16* Wkb = (__bf16*)carve((size_t)DIM * DIM * 2);
  __bf16* Wvb = (__bf16*)carve((size_t)DIM * DIM * 2);
  __bf16* Wob = (__bf16*)carve((size_t)DIM * DIM * 2);
  __bf16* Pc  = (__bf16*)carve((size_t)BATCH * NTRI * 16384 * 2);  // 69.2 MB
  float*  rlr = (float*)carve((size_t)TOK * 4);
  if((size_t)(p - (char*)d_ws) > ws_size) return;

  const long nW4 = (long)DIM * DIM / 4;
  dim3 g4((unsigned)((nW4 + 255) / 256), 4);
  hipMemsetAsync(rlr, 0, (size_t)TOK * 4, stream);     // row-sum accumulators
  hipMemsetAsync(att1, 0, tb, stream);                 // second K-split partial
  cvt4_kernel<<<g4, 256, 0, stream>>>(Wq, Wk, Wv, Wo, Wqb, Wkb, Wvb, Wob, nW4);

  // Q, K, V^T projections in one dispatch; f32 staging with T14 prefetch
  proj_qkv<<<dim3(384, 3), 512, 0, stream>>>(query, key_, value, Wqb, Wkb, Wvb,
                                             bq, bk, bv, qb, kb, vbT);

  // QK^T with fused exp + row-sum atomics (2-phase, 3 blocks/CU)
  qk_kernel<<<dim3(272, BATCH), 512, 0, stream>>>(qb, kb, Pc, rlr);

  // P.V with balanced 2-way K-split (756 blocks, longest chunks first)
  pv_kernel<<<dim3(12, 63), 512, 0, stream>>>(Pc, rlr, vbT, att0, att1);

  // output projection, att0+att1 fused into A-staging -> fp32 d_out
  oproj<<<384, 512, 0, stream>>>(att0, att1, Wob, bo, (float*)d_out);
}